// Round 9
// baseline (581.582 us; speedup 1.0000x reference)
//
#include <hip/hip_runtime.h>
#include <stdint.h>

#define LN_EPS 1e-5f

// LayerNorm(C) + ReLU over a register array. Fully unrolled (reg arrays need
// compile-time indices).
template <int C>
__device__ __forceinline__ void ln_relu(float (&a)[C], const float* __restrict__ g,
                                        const float* __restrict__ b, float inv_c) {
  float p0 = 0.f, p1 = 0.f, p2 = 0.f, p3 = 0.f;
#pragma unroll
  for (int j = 0; j < C; j += 4) { p0 += a[j]; p1 += a[j + 1]; p2 += a[j + 2]; p3 += a[j + 3]; }
  float mu = ((p0 + p1) + (p2 + p3)) * inv_c;
  float q0 = 0.f, q1 = 0.f, q2 = 0.f, q3 = 0.f;
#pragma unroll
  for (int j = 0; j < C; j += 4) {
    float d0 = a[j] - mu, d1 = a[j + 1] - mu, d2 = a[j + 2] - mu, d3 = a[j + 3] - mu;
    a[j] = d0; a[j + 1] = d1; a[j + 2] = d2; a[j + 3] = d3;
    q0 = fmaf(d0, d0, q0); q1 = fmaf(d1, d1, q1); q2 = fmaf(d2, d2, q2); q3 = fmaf(d3, d3, q3);
  }
  float var = ((q0 + q1) + (q2 + q3)) * inv_c;
  float rs = rsqrtf(var + LN_EPS);
#pragma unroll
  for (int j = 0; j < C; ++j) {
    float t = a[j] * rs;
    t = fmaf(t, g[j], b[j]);
    a[j] = fmaxf(t, 0.f);
  }
}

// R9: 2 rows/thread in the ROLLED R5/R6 structure, scalar weight feed, no
// VGPR cap. (R8's LDS feed reverted: measured DS-throughput-bound, 223us ≈
// 57.5k DS-instrs/CU × ~10cyc; scalar feed at 157us wins.)
// Theory: scalar feed is latency-limited at SGPR pipeline depth ~2 — per
// kk-step 32 weight dwords feed only 64 issue-cycles of FMA vs ~120-200cyc
// K$ latency => ~50% inner-loop efficiency. 2 rows/thread doubles FMAs per
// weight batch (64 FMAs, 128-190cyc issue) => latency covered at same depth.
// R3's 2-row failure causes are retired individually: spill was the
// launch_bounds(256,4) 64-VGPR cap (R3, lifted); I-stream was the 80KB full
// unroll (R4, now rolled ~15KB/2rows = less I$ per row than R5). VGPR ~140
// -> 3 waves/SIMD; R7 measured occupancy-insensitivity (4->8 waves = 0%).
// Keeps R6 dist-1 x-prefetch for both rows.
// Tripwire: WRITE_SIZE must stay 16.02MB; growth = spill => drop prefetch.
// Predict: kernel ~145 -> 105-125us (bench ~455-485); if unchanged, pivot
// to bf16 MFMA.
__global__ __launch_bounds__(256) void dec_kernel(
    const float* __restrict__ x,
    const float* __restrict__ w1, const float* __restrict__ g1, const float* __restrict__ b1,
    const float* __restrict__ w2, const float* __restrict__ g2, const float* __restrict__ b2,
    const float* __restrict__ w3, const float* __restrict__ b3,
    float* __restrict__ out, int N, int HW)
{
  const int t  = threadIdx.x;
  const int r0 = blockIdx.x * 512 + t;
  if (r0 >= N) return;
  const int r1    = r0 + 256;
  const bool has1 = (r1 < N);
  const int r1c   = has1 ? r1 : r0;   // clamp: duplicate work, store discarded

  const float4* __restrict__ xp0 = (const float4*)(x + (size_t)r0  * 64);
  const float4* __restrict__ xp1 = (const float4*)(x + (size_t)r1c * 64);

  // ---- layer 1: K=64 -> 32, rolled over 4 chunks, dist-1 prefetch, 2 rows ----
  float acc0[32], acc1[32];
#pragma unroll
  for (int j = 0; j < 32; ++j) { acc0[j] = 0.f; acc1[j] = 0.f; }

  float4 a0 = xp0[0], a1 = xp0[1], a2 = xp0[2], a3 = xp0[3];
  float4 b0 = xp1[0], b1v = xp1[1], b2v = xp1[2], b3v = xp1[3];

#pragma unroll 1
  for (int c = 0; c < 4; ++c) {
    const int nc = (c < 3) ? (c + 1) : 3;   // clamped last iter: L1-hot reload
    float4 na0 = xp0[nc * 4 + 0], na1 = xp0[nc * 4 + 1];
    float4 na2 = xp0[nc * 4 + 2], na3 = xp0[nc * 4 + 3];
    float4 nb0 = xp1[nc * 4 + 0], nb1 = xp1[nc * 4 + 1];
    float4 nb2 = xp1[nc * 4 + 2], nb3 = xp1[nc * 4 + 3];

    const float* __restrict__ wbase = w1 + c * 16 * 32;
#pragma unroll
    for (int q = 0; q < 4; ++q) {
      const float4 xa = (q == 0) ? a0 : (q == 1) ? a1 : (q == 2) ? a2 : a3;
      const float4 xb = (q == 0) ? b0 : (q == 1) ? b1v : (q == 2) ? b2v : b3v;
#pragma unroll
      for (int kk = 0; kk < 4; ++kk) {
        const float xk0 = (kk == 0) ? xa.x : (kk == 1) ? xa.y : (kk == 2) ? xa.z : xa.w;
        const float xk1 = (kk == 0) ? xb.x : (kk == 1) ? xb.y : (kk == 2) ? xb.z : xb.w;
        const float* __restrict__ wrow = wbase + (q * 4 + kk) * 32;  // uniform -> s_load
#pragma unroll
        for (int j = 0; j < 32; ++j) {
          const float w = wrow[j];                 // one SGPR dword feeds 2 FMAs
          acc0[j] = fmaf(xk0, w, acc0[j]);
          acc1[j] = fmaf(xk1, w, acc1[j]);
        }
      }
    }
    a0 = na0; a1 = na1; a2 = na2; a3 = na3;
    b0 = nb0; b1v = nb1; b2v = nb2; b3v = nb3;
  }

  ln_relu<32>(acc0, g1, b1, 0.03125f);
  ln_relu<32>(acc1, g1, b1, 0.03125f);

  // ---- layer 2: K=32 -> 16, two rows share each s_load batch ----
  float a20[16], a21[16];
#pragma unroll
  for (int j = 0; j < 16; ++j) { a20[j] = 0.f; a21[j] = 0.f; }
#pragma unroll
  for (int k = 0; k < 32; ++k) {
    const float h0 = acc0[k], h1 = acc1[k];
    const float* __restrict__ wrow = w2 + k * 16;       // uniform -> s_load
#pragma unroll
    for (int j = 0; j < 16; ++j) {
      const float w = wrow[j];
      a20[j] = fmaf(h0, w, a20[j]);
      a21[j] = fmaf(h1, w, a21[j]);
    }
  }

  ln_relu<16>(a20, g2, b2, 0.0625f);
  ln_relu<16>(a21, g2, b2, 0.0625f);

  // ---- layer 3 + channel L2-normalize, two rows share w3 ----
  float o00 = b3[0], o01 = b3[1], o02 = b3[2];
  float o10 = b3[0], o11 = b3[1], o12 = b3[2];
#pragma unroll
  for (int k = 0; k < 16; ++k) {
    const float wa = w3[k * 3 + 0], wb = w3[k * 3 + 1], wc = w3[k * 3 + 2];
    o00 = fmaf(a20[k], wa, o00); o01 = fmaf(a20[k], wb, o01); o02 = fmaf(a20[k], wc, o02);
    o10 = fmaf(a21[k], wa, o10); o11 = fmaf(a21[k], wb, o11); o12 = fmaf(a21[k], wc, o12);
  }

  {
    const float nsq = fmaf(o00, o00, fmaf(o01, o01, o02 * o02));
    const float inv = rsqrtf(fmaxf(nsq, 1e-24f));  // == 1/max(||o||,1e-12)
    o00 *= inv; o01 *= inv; o02 *= inv;
  }
  {
    const float nsq = fmaf(o10, o10, fmaf(o11, o11, o12 * o12));
    const float inv = rsqrtf(fmaxf(nsq, 1e-24f));
    o10 *= inv; o11 *= inv; o12 *= inv;
  }

  // out[b][c][h][w]; flat = b*3*HW + c*HW + p; lanes consecutive in p -> coalesced
  {
    const unsigned bb = (unsigned)r0 / (unsigned)HW;
    const unsigned p  = (unsigned)r0 - bb * (unsigned)HW;
    const size_t ob = (size_t)bb * 3 * HW + p;
    out[ob] = o00; out[ob + HW] = o01; out[ob + 2 * HW] = o02;
  }
  if (has1) {
    const unsigned bb = (unsigned)r1 / (unsigned)HW;
    const unsigned p  = (unsigned)r1 - bb * (unsigned)HW;
    const size_t ob = (size_t)bb * 3 * HW + p;
    out[ob] = o10; out[ob + HW] = o11; out[ob + 2 * HW] = o12;
  }
}

extern "C" void kernel_launch(void* const* d_in, const int* in_sizes, int n_in,
                              void* d_out, int out_size, void* d_ws, size_t ws_size,
                              hipStream_t stream) {
  const float* x  = (const float*)d_in[0];
  const float* w1 = (const float*)d_in[1];
  const float* g1 = (const float*)d_in[2];
  const float* b1 = (const float*)d_in[3];
  const float* w2 = (const float*)d_in[4];
  const float* g2 = (const float*)d_in[5];
  const float* b2 = (const float*)d_in[6];
  const float* w3 = (const float*)d_in[7];
  const float* b3 = (const float*)d_in[8];
  float* out = (float*)d_out;

  const int N  = in_sizes[0] / 64;  // rows
  const int HW = N / 4;             // B = 4 per reference setup
  const int nblocks = (N + 511) / 512;   // 512 rows per block (2 per thread)
  dec_kernel<<<nblocks, 256, 0, stream>>>(x, w1, g1, b1, w2, g2, b2, w3, b3, out, N, HW);
}